// Round 5
// baseline (298.826 us; speedup 1.0000x reference)
//
#include <hip/hip_runtime.h>
#include <hip/hip_bf16.h>

typedef float floatx4 __attribute__((ext_vector_type(4)));
typedef short bhalf8  __attribute__((ext_vector_type(8)));
typedef unsigned short ush;
typedef unsigned int uint;

#define EPS 1e-5f

constexpr int Bb = 8, S = 256, T = 64, Dc = 100;
constexpr int SH = 255;   // conv2/y2 rows (S-H+1)
constexpr int SO = 254;   // final logit rows
constexpr int CK = 128;   // padded input-channel (K per h-tap)
constexpr int CR = 112;   // padded output-channel rows (7 x 16)
constexpr int LSTR = 136; // LDS row stride in bf16 (272B): 2-way bank aliasing only (free)

// workspace layout (bytes)
constexpr size_t OFF_U1   = 0;                            // f32[128]
constexpr size_t OFF_S2   = 512;                          // f32[128]
constexpr size_t OFF_W30  = 1024;                         // f32[128]
constexpr size_t OFF_W31  = 1536;                         // f32[128]
constexpr size_t OFF_W1T  = 2048;                         // f32 [128][128]
constexpr size_t OFF_W1KT = OFF_W1T + 65536;              // f32 [64][128]
constexpr size_t OFF_W2P  = OFF_W1KT + 32768;             // ush [2][112][128]
constexpr size_t OFF_AQS  = OFF_W2P + 57344;              // f32 [8][255][128]  Aq*s1+u1
constexpr size_t OFF_AQE  = OFF_AQS + (size_t)Bb*SH*CK*4; // f32 [8][255][128]  Aq*s2+u2
constexpr size_t OFF_AKF  = OFF_AQE + (size_t)Bb*SH*CK*4; // f32 [8][16][4][64][8]  Ak*s1, MFMA-B lane order
constexpr size_t OFF_AKEF = OFF_AKF + (size_t)Bb*16*4*64*8*4; // f32 [8][16][7][64][4] Ak*s2, MFMA-C lane order
constexpr size_t OFF_Z0   = OFF_AKEF + (size_t)Bb*16*7*64*4*4; // f32 [8][255][256]
constexpr size_t OFF_Z1   = OFF_Z0 + (size_t)Bb*SH*S*4;   // f32 [8][255][256]

__device__ __forceinline__ uint pkbf(float lo, float hi) {
    // pack two f32 -> bf16x2 (round-half-up via +0x8000, take high halves with one v_perm)
    uint a = __float_as_uint(lo) + 0x8000u;
    uint b = __float_as_uint(hi) + 0x8000u;
    return __builtin_amdgcn_perm(b, a, 0x07060302u);
}

// ---------------- prep0: W1 transposes + W2 pack + per-channel params ----------------
__global__ __launch_bounds__(128) void k_prep0(const float* __restrict__ W1, const float* __restrict__ W2,
                                               const float* __restrict__ g1, const float* __restrict__ be1,
                                               const float* __restrict__ m1, const float* __restrict__ var1,
                                               const float* __restrict__ g2, const float* __restrict__ var2,
                                               const float* __restrict__ W3,
                                               float* __restrict__ W1T, float* __restrict__ W1kT,
                                               ush* __restrict__ W2p,
                                               float* __restrict__ U1, float* __restrict__ S2,
                                               float* __restrict__ W30, float* __restrict__ W31) {
    const int bid = blockIdx.x, tid = threadIdx.x;
    if (bid < 128) {                       // W1T[k][c] = W1[c][k]  (k = 2t+h, first 64 t-rows)
        int k = bid, c = tid;
        W1T[k * 128 + c] = (c < Dc) ? W1[(size_t)c * 256 + k] : 0.f;
    } else if (bid < 192) {                // W1kT[t][c] = W1[c][64+t][0] + W1[c][64+t][1]
        int t = bid - 128, c = tid;
        W1kT[t * 128 + c] = (c < Dc) ? (W1[(size_t)c * 256 + 128 + 2 * t] + W1[(size_t)c * 256 + 129 + 2 * t]) : 0.f;
    } else if (bid < 416) {                // W2 pack -> [h][c(112)][c'(128)] bf16
        int idx = (bid - 192) * 128 + tid;
        int h = idx / (CR * CK);
        int rem = idx % (CR * CK);
        int c = rem / CK, cp = rem % CK;
        float v = (c < Dc && cp < Dc) ? W2[((size_t)c * Dc + cp) * 2 + h] : 0.f;
        __hip_bfloat16 bv = __float2bfloat16(v);
        W2p[idx] = *reinterpret_cast<ush*>(&bv);
    } else {                               // params
        int c = tid;
        float u1 = 0.f, s2 = 0.f, w0 = 0.f, w1 = 0.f;
        if (c < Dc) {
            float sg1 = g1[c] / sqrtf(var1[c] + EPS);
            u1 = be1[c] - m1[c] * sg1;
            s2 = g2[c] / sqrtf(var2[c] + EPS);
            w0 = W3[c * 2 + 0];
            w1 = W3[c * 2 + 1];
        }
        U1[c] = u1; S2[c] = s2; W30[c] = w0; W31[c] = w1;
    }
}

// ---------------- prep1: Aq rows (flat) / Ak rows (pre-swizzled MFMA lane order) ----------------
__global__ __launch_bounds__(128) void k_prep1(const float* __restrict__ q, const float* __restrict__ kin,
                                               const float* __restrict__ b1,
                                               const float* __restrict__ W1T, const float* __restrict__ W1kT,
                                               const float* __restrict__ g1, const float* __restrict__ be1,
                                               const float* __restrict__ m1, const float* __restrict__ var1,
                                               const float* __restrict__ g2, const float* __restrict__ be2,
                                               const float* __restrict__ m2, const float* __restrict__ var2,
                                               const float* __restrict__ b2,
                                               float* __restrict__ AqS, float* __restrict__ AqE,
                                               float* __restrict__ AkF, float* __restrict__ AkEF) {
    __shared__ float xs[128];
    const int bid = blockIdx.x, tid = threadIdx.x;
    const int c = tid;
    float s1 = 0.f, u1 = 0.f, s2 = 0.f, u2 = 0.f;
    if (c < Dc) {
        s1 = g1[c] / sqrtf(var1[c] + EPS);
        u1 = be1[c] - m1[c] * s1;
        s2 = g2[c] / sqrtf(var2[c] + EPS);
        u2 = (b2[c] - m2[c]) * s2 + be2[c];
    }
    if (bid < SH * Bb) {          // Aq row: i = bid % SH, b = bid / SH
        const int i = bid % SH, b = bid / SH;
        if (tid < 64) xs[2 * tid]            = q[((size_t)b * S + i) * T + tid];
        else          xs[2 * (tid - 64) + 1] = q[((size_t)b * S + i + 1) * T + (tid - 64)];
        __syncthreads();
        float s = 0.f;
        #pragma unroll 8
        for (int k = 0; k < 128; ++k) s = fmaf(xs[k], W1T[k * 128 + c], s);
        if (c < Dc) s += b1[c]; else s = 0.f;
        size_t row = ((size_t)b * SH + i) * CK + c;
        AqS[row] = s * s1 + u1;
        AqE[row] = s * s2 + u2;
    } else {                      // Ak row -> swizzled fragment buffers
        const int r = bid - SH * Bb;
        const int j = r % S, b = r / S;
        if (tid < 64) xs[tid] = kin[((size_t)b * S + j) * T + tid];
        __syncthreads();
        float s = 0.f;
        #pragma unroll 8
        for (int t = 0; t < 64; ++t) s = fmaf(xs[t], W1kT[t * 128 + c], s);
        const int j16 = j >> 4, ln = j & 15;
        // B-fragment layout: [b][j16][ks(4)][lane(64)=q*16+ln][e(8)]
        {
            int ks = c >> 5, qq = (c >> 3) & 3, e = c & 7;
            AkF[((((size_t)b * 16 + j16) * 4 + ks) * 64 + qq * 16 + ln) * 8 + e] = s * s1;
        }
        // C-fragment layout: [b][j16][ct(7)][lane(64)=q*16+ln][r(4)]
        if (c < 112) {
            int ct = c >> 4, q2 = (c >> 2) & 3, rr = c & 3;
            AkEF[((((size_t)b * 16 + j16) * 7 + ct) * 64 + q2 * 16 + ln) * 4 + rr] = s * s2;
        }
    }
}

// ---------------- main: per-lane y1 frags (coalesced) -> MFMA conv2 -> fused bn2/relu/conv3 taps ----------------
__global__ __launch_bounds__(256, 4) void k_main(const float* __restrict__ AqS, const float* __restrict__ AqE,
                                                 const float* __restrict__ AkF, const float* __restrict__ AkEF,
                                                 const ush* __restrict__ W2p,
                                                 const float* __restrict__ U1, const float* __restrict__ S2,
                                                 const float* __restrict__ W30f, const float* __restrict__ W31f,
                                                 float* __restrict__ Z0, float* __restrict__ Z1) {
    __shared__ __align__(16) ush W2s[CR * LSTR];   // W2[c][c'] for current h (~30 KB)
    const int tid = threadIdx.x;
    const int wv = tid >> 6, lane = tid & 63, ln = lane & 15, quad = lane >> 4;
    const int jt = blockIdx.x, ip = blockIdx.y, b = blockIdx.z;
    const int j0 = jt << 7;
    const int j16A = (jt << 3) + (wv << 1);

    floatx4 acc0[7], acc1[7];
    #pragma unroll
    for (int ct = 0; ct < 7; ++ct) {
        acc0[ct] = (floatx4){0.f, 0.f, 0.f, 0.f};
        acc1[ct] = (floatx4){0.f, 0.f, 0.f, 0.f};
    }

    const float* fA = AkF + ((size_t)(b * 16 + j16A) * 4 * 64 + lane) * 8;   // lane*32B coalesced
    const float* fB = fA + 4 * 64 * 8;

    for (int h = 0; h < 2; ++h) {
        __syncthreads();
        #pragma unroll
        for (int it = 0; it < 7; ++it) {           // stage W2 half (coalesced 16B)
            int idx = it * 256 + tid;
            int row = idx >> 4, ch = idx & 15;
            *reinterpret_cast<uint4*>(&W2s[row * LSTR + ch * 8]) =
                *reinterpret_cast<const uint4*>(&W2p[(h * CR + row) * CK + ch * 8]);
        }
        __syncthreads();
        const int i2 = ip + h;
        if (i2 == 0) {
            // padded row: y1 = relu(u1), j-independent
            #pragma unroll
            for (int ks = 0; ks < 4; ++ks) {
                const int k0 = ks * 32 + quad * 8;
                const float4 qa = *reinterpret_cast<const float4*>(U1 + k0);
                const float4 qb = *reinterpret_cast<const float4*>(U1 + k0 + 4);
                uint4 p;
                p.x = pkbf(fmaxf(qa.x, 0.f), fmaxf(qa.y, 0.f));
                p.y = pkbf(fmaxf(qa.z, 0.f), fmaxf(qa.w, 0.f));
                p.z = pkbf(fmaxf(qb.x, 0.f), fmaxf(qb.y, 0.f));
                p.w = pkbf(fmaxf(qb.z, 0.f), fmaxf(qb.w, 0.f));
                const bhalf8 bf0 = *reinterpret_cast<bhalf8*>(&p);
                #pragma unroll
                for (int ct = 0; ct < 7; ++ct) {
                    const bhalf8 af = *reinterpret_cast<const bhalf8*>(&W2s[(ct * 16 + ln) * LSTR + k0]);
                    acc0[ct] = __builtin_amdgcn_mfma_f32_16x16x32_bf16(af, bf0, acc0[ct], 0, 0, 0);
                    acc1[ct] = __builtin_amdgcn_mfma_f32_16x16x32_bf16(af, bf0, acc1[ct], 0, 0, 0);
                }
            }
        } else {
            const float* aqrow = AqS + (size_t)(b * SH + (i2 - 1)) * CK;
            #pragma unroll
            for (int ks = 0; ks < 4; ++ks) {
                const int k0 = ks * 32 + quad * 8;
                const float4 qa = *reinterpret_cast<const float4*>(aqrow + k0);
                const float4 qb = *reinterpret_cast<const float4*>(aqrow + k0 + 4);
                const float4 a0 = *reinterpret_cast<const float4*>(fA + ks * 512);
                const float4 a1 = *reinterpret_cast<const float4*>(fA + ks * 512 + 4);
                const float4 b0 = *reinterpret_cast<const float4*>(fB + ks * 512);
                const float4 b1 = *reinterpret_cast<const float4*>(fB + ks * 512 + 4);
                uint4 p, rr;
                p.x  = pkbf(fmaxf(qa.x + a0.x, 0.f), fmaxf(qa.y + a0.y, 0.f));
                p.y  = pkbf(fmaxf(qa.z + a0.z, 0.f), fmaxf(qa.w + a0.w, 0.f));
                p.z  = pkbf(fmaxf(qb.x + a1.x, 0.f), fmaxf(qb.y + a1.y, 0.f));
                p.w  = pkbf(fmaxf(qb.z + a1.z, 0.f), fmaxf(qb.w + a1.w, 0.f));
                rr.x = pkbf(fmaxf(qa.x + b0.x, 0.f), fmaxf(qa.y + b0.y, 0.f));
                rr.y = pkbf(fmaxf(qa.z + b0.z, 0.f), fmaxf(qa.w + b0.w, 0.f));
                rr.z = pkbf(fmaxf(qb.x + b1.x, 0.f), fmaxf(qb.y + b1.y, 0.f));
                rr.w = pkbf(fmaxf(qb.z + b1.z, 0.f), fmaxf(qb.w + b1.w, 0.f));
                const bhalf8 bf0 = *reinterpret_cast<bhalf8*>(&p);
                const bhalf8 bf1 = *reinterpret_cast<bhalf8*>(&rr);
                #pragma unroll
                for (int ct = 0; ct < 7; ++ct) {
                    const bhalf8 af = *reinterpret_cast<const bhalf8*>(&W2s[(ct * 16 + ln) * LSTR + k0]);
                    acc0[ct] = __builtin_amdgcn_mfma_f32_16x16x32_bf16(af, bf0, acc0[ct], 0, 0, 0);
                    acc1[ct] = __builtin_amdgcn_mfma_f32_16x16x32_bf16(af, bf1, acc1[ct], 0, 0, 0);
                }
            }
        }
    }

    // epilogue: ta = relu(acc*s2 + AqE[ip] + AkE[j]); conv3 taps z0/z1 reduced over c
    float z0a = 0.f, z1a = 0.f, z0b = 0.f, z1b = 0.f;
    const float* aqer = AqE + (size_t)(b * SH + ip) * CK;
    const float* eA = AkEF + ((size_t)(b * 16 + j16A) * 7 * 64 + lane) * 4;  // lane*16B coalesced
    const float* eB = eA + 7 * 64 * 4;
    #pragma unroll
    for (int ct = 0; ct < 7; ++ct) {
        const int c = ct * 16 + (quad << 2);
        const float4 aq  = *reinterpret_cast<const float4*>(aqer + c);
        const float4 aka = *reinterpret_cast<const float4*>(eA + ct * 256);
        const float4 akb = *reinterpret_cast<const float4*>(eB + ct * 256);
        const float4 s2  = *reinterpret_cast<const float4*>(S2 + c);
        const float4 w0  = *reinterpret_cast<const float4*>(W30f + c);
        const float4 w1  = *reinterpret_cast<const float4*>(W31f + c);
        const float aqv[4] = {aq.x, aq.y, aq.z, aq.w};
        const float kav[4] = {aka.x, aka.y, aka.z, aka.w};
        const float kbv[4] = {akb.x, akb.y, akb.z, akb.w};
        const float s2v[4] = {s2.x, s2.y, s2.z, s2.w};
        const float w0v[4] = {w0.x, w0.y, w0.z, w0.w};
        const float w1v[4] = {w1.x, w1.y, w1.z, w1.w};
        #pragma unroll
        for (int r = 0; r < 4; ++r) {
            float ta = fmaxf(fmaf(acc0[ct][r], s2v[r], aqv[r] + kav[r]), 0.f);
            z0a = fmaf(ta, w0v[r], z0a);
            z1a = fmaf(ta, w1v[r], z1a);
            float tb = fmaxf(fmaf(acc1[ct][r], s2v[r], aqv[r] + kbv[r]), 0.f);
            z0b = fmaf(tb, w0v[r], z0b);
            z1b = fmaf(tb, w1v[r], z1b);
        }
    }
    z0a += __shfl_xor(z0a, 16, 64); z0a += __shfl_xor(z0a, 32, 64);
    z1a += __shfl_xor(z1a, 16, 64); z1a += __shfl_xor(z1a, 32, 64);
    z0b += __shfl_xor(z0b, 16, 64); z0b += __shfl_xor(z0b, 32, 64);
    z1b += __shfl_xor(z1b, 16, 64); z1b += __shfl_xor(z1b, 32, 64);
    if (lane < 16) {
        size_t zi = (size_t)(b * SH + ip) * S + j0 + wv * 32 + lane;
        Z0[zi] = z0a; Z1[zi] = z1a;
        Z0[zi + 16] = z0b; Z1[zi + 16] = z1b;
    }
}

// ---------------- softmax + attn@v: one wave per output row, no barriers ----------------
__global__ __launch_bounds__(256) void k_soft(const float* __restrict__ Z0, const float* __restrict__ Z1,
                                              const float* __restrict__ v,
                                              const float* __restrict__ b3,
                                              float* __restrict__ outp,
                                              float* __restrict__ attnp) {
    __shared__ float attn_s[4][256];
    const int wv = threadIdx.x >> 6, lane = threadIdx.x & 63;
    const int i = blockIdx.x * 4 + wv;
    const int b = blockIdx.y;
    if (i >= SO) return;
    const float b3f = b3[0];
    const size_t zr = (size_t)(b * SH + i) * S;
    const float4 z0 = *reinterpret_cast<const float4*>(Z0 + zr + lane * 4);
    const float4 z1 = *reinterpret_cast<const float4*>(Z1 + zr + S + lane * 4);
    float l0 = (z0.x + z1.x + b3f) * 0.1f;
    float l1 = (z0.y + z1.y + b3f) * 0.1f;
    float l2 = (z0.z + z1.z + b3f) * 0.1f;
    float l3 = (z0.w + z1.w + b3f) * 0.1f;

    float mx = fmaxf(fmaxf(l0, l1), fmaxf(l2, l3));
    #pragma unroll
    for (int o = 1; o < 64; o <<= 1) mx = fmaxf(mx, __shfl_xor(mx, o, 64));
    float e0 = __expf(l0 - mx), e1 = __expf(l1 - mx), e2 = __expf(l2 - mx), e3 = __expf(l3 - mx);
    float sm = e0 + e1 + e2 + e3;
    #pragma unroll
    for (int o = 1; o < 64; o <<= 1) sm += __shfl_xor(sm, o, 64);
    const float inv = 1.f / sm;
    const float a0 = e0 * inv, a1 = e1 * inv, a2 = e2 * inv, a3 = e3 * inv;
    *reinterpret_cast<float4*>(attnp + (size_t)(b * SO + i) * S + lane * 4) = make_float4(a0, a1, a2, a3);
    *reinterpret_cast<float4*>(&attn_s[wv][lane * 4]) = make_float4(a0, a1, a2, a3);
    // same-wave LDS RAW: no barrier needed

    const float* vb = v + (size_t)b * S * T + lane;
    float acc = 0.f;
    #pragma unroll 8
    for (int j = 0; j < 256; ++j)
        acc = fmaf(attn_s[wv][j], vb[(size_t)j * T], acc);
    outp[(size_t)(b * SO + i) * T + lane] = acc;
}

extern "C" void kernel_launch(void* const* d_in, const int* in_sizes, int n_in,
                              void* d_out, int out_size, void* d_ws, size_t ws_size,
                              hipStream_t stream) {
    const float* q    = (const float*)d_in[0];
    const float* kin  = (const float*)d_in[1];
    const float* vin  = (const float*)d_in[2];
    const float* W1   = (const float*)d_in[3];
    const float* b1   = (const float*)d_in[4];
    const float* g1   = (const float*)d_in[5];
    const float* be1  = (const float*)d_in[6];
    const float* m1   = (const float*)d_in[7];
    const float* var1 = (const float*)d_in[8];
    const float* W2   = (const float*)d_in[9];
    const float* b2   = (const float*)d_in[10];
    const float* g2   = (const float*)d_in[11];
    const float* be2  = (const float*)d_in[12];
    const float* m2   = (const float*)d_in[13];
    const float* var2 = (const float*)d_in[14];
    const float* W3   = (const float*)d_in[15];
    const float* b3   = (const float*)d_in[16];

    char* ws = (char*)d_ws;
    float* U1   = (float*)(ws + OFF_U1);
    float* S2p  = (float*)(ws + OFF_S2);
    float* W30  = (float*)(ws + OFF_W30);
    float* W31  = (float*)(ws + OFF_W31);
    float* W1T  = (float*)(ws + OFF_W1T);
    float* W1kT = (float*)(ws + OFF_W1KT);
    ush*   W2p  = (ush*)(ws + OFF_W2P);
    float* AqS  = (float*)(ws + OFF_AQS);
    float* AqE  = (float*)(ws + OFF_AQE);
    float* AkF  = (float*)(ws + OFF_AKF);
    float* AkEF = (float*)(ws + OFF_AKEF);
    float* Z0   = (float*)(ws + OFF_Z0);
    float* Z1   = (float*)(ws + OFF_Z1);

    float* outp  = (float*)d_out;
    float* attnp = outp + (size_t)Bb * SO * T;

    k_prep0<<<417, 128, 0, stream>>>(W1, W2, g1, be1, m1, var1, g2, var2, W3,
                                     W1T, W1kT, W2p, U1, S2p, W30, W31);
    k_prep1<<<SH * Bb + S * Bb, 128, 0, stream>>>(q, kin, b1, W1T, W1kT,
                                                  g1, be1, m1, var1, g2, be2, m2, var2, b2,
                                                  AqS, AqE, AkF, AkEF);
    k_main<<<dim3(2, SH, Bb), 256, 0, stream>>>(AqS, AqE, AkF, AkEF, W2p, U1, S2p, W30, W31, Z0, Z1);
    k_soft<<<dim3((SO + 3) / 4, Bb), 256, 0, stream>>>(Z0, Z1, vin, b3, outp, attnp);
}

// Round 6
// 233.010 us; speedup vs baseline: 1.2825x; 1.2825x over previous
//
#include <hip/hip_runtime.h>
#include <hip/hip_bf16.h>

typedef float floatx4 __attribute__((ext_vector_type(4)));
typedef short bhalf8  __attribute__((ext_vector_type(8)));
typedef unsigned short ush;
typedef unsigned int uint;

#define EPS 1e-5f

constexpr int Bb = 8, S = 256, T = 64, Dc = 100;
constexpr int SH = 255;   // conv2/y2 rows (S-H+1)
constexpr int SO = 254;   // final logit rows
constexpr int CK = 128;   // padded input-channel (K per h-tap)
constexpr int CR = 112;   // padded output-channel rows (7 x 16)
constexpr int LSTR = 136; // LDS row stride in bf16 (272B)

// workspace layout (bytes)
constexpr size_t OFF_U1  = 0;                             // f32[128]
constexpr size_t OFF_S2  = 512;                           // f32[128]
constexpr size_t OFF_W30 = 1024;                          // f32[128]
constexpr size_t OFF_W31 = 1536;                          // f32[128]
constexpr size_t OFF_W2P = 2048;                          // ush [2][112][128]
constexpr size_t OFF_AQS = OFF_W2P + 57344;               // f32 [8][255][128]  Aq*s1+u1
constexpr size_t OFF_AQE = OFF_AQS + (size_t)Bb*SH*CK*4;  // f32 [8][255][128]  Aq*s2+u2
constexpr size_t OFF_AKS = OFF_AQE + (size_t)Bb*SH*CK*4;  // f32 [8][256][128]  Ak*s1
constexpr size_t OFF_AKE = OFF_AKS + (size_t)Bb*S*CK*4;   // f32 [8][256][128]  Ak*s2
constexpr size_t OFF_Z0  = OFF_AKE + (size_t)Bb*S*CK*4;   // f32 [8][255][256]
constexpr size_t OFF_Z1  = OFF_Z0 + (size_t)Bb*SH*S*4;    // f32 [8][255][256]

constexpr int NAQ = SH * Bb;   // 2040 Aq-row blocks
constexpr int NAK = S * Bb;    // 2048 Ak-row blocks
constexpr int NW2 = 224;       // W2-pack blocks (224*128 = 2*112*128)

__device__ __forceinline__ uint pkbf(float lo, float hi) {
    // pack two f32 -> bf16x2 (+0x8000 round, high halves via one v_perm)
    uint a = __float_as_uint(lo) + 0x8000u;
    uint b = __float_as_uint(hi) + 0x8000u;
    return __builtin_amdgcn_perm(b, a, 0x07060302u);
}

// ---------------- k_prep (single launch): params + W2 pack + Aq/Ak rows ----------------
__global__ __launch_bounds__(128) void k_prep(const float* __restrict__ q, const float* __restrict__ kin,
                                              const float* __restrict__ W1, const float* __restrict__ b1,
                                              const float* __restrict__ g1, const float* __restrict__ be1,
                                              const float* __restrict__ m1, const float* __restrict__ var1,
                                              const float* __restrict__ W2, const float* __restrict__ b2,
                                              const float* __restrict__ g2, const float* __restrict__ be2,
                                              const float* __restrict__ m2, const float* __restrict__ var2,
                                              const float* __restrict__ W3,
                                              ush* __restrict__ W2p,
                                              float* __restrict__ U1, float* __restrict__ S2,
                                              float* __restrict__ W30, float* __restrict__ W31,
                                              float* __restrict__ AqS, float* __restrict__ AqE,
                                              float* __restrict__ AkS, float* __restrict__ AkE) {
    __shared__ float xs[128];
    const int bid = blockIdx.x, tid = threadIdx.x;
    const int c = tid;

    if (bid >= NAQ + NAK) {
        int r = bid - NAQ - NAK;
        if (r < NW2) {                 // W2 pack -> [h][c(112)][cp(128)] bf16, zero-padded
            int idx = r * 128 + tid;
            int h = idx / (CR * CK);
            int rem = idx % (CR * CK);
            int cc = rem / CK, cp = rem % CK;
            float v = (cc < Dc && cp < Dc) ? W2[((size_t)cc * Dc + cp) * 2 + h] : 0.f;
            __hip_bfloat16 bv = __float2bfloat16(v);
            W2p[idx] = *reinterpret_cast<ush*>(&bv);
        } else {                        // per-channel params
            float u1 = 0.f, s2 = 0.f, w0 = 0.f, w1 = 0.f;
            if (c < Dc) {
                float sg1 = g1[c] / sqrtf(var1[c] + EPS);
                u1 = be1[c] - m1[c] * sg1;
                s2 = g2[c] / sqrtf(var2[c] + EPS);
                w0 = W3[c * 2 + 0];
                w1 = W3[c * 2 + 1];
            }
            U1[c] = u1; S2[c] = s2; W30[c] = w0; W31[c] = w1;
        }
        return;
    }

    float s1 = 0.f, u1 = 0.f, s2 = 0.f, u2 = 0.f;
    if (c < Dc) {
        s1 = g1[c] / sqrtf(var1[c] + EPS);
        u1 = be1[c] - m1[c] * s1;
        s2 = g2[c] / sqrtf(var2[c] + EPS);
        u2 = (b2[c] - m2[c]) * s2 + be2[c];
    }
    if (bid < NAQ) {               // Aq row: i = bid % SH, b = bid / SH
        const int i = bid % SH, b = bid / SH;
        if (tid < 64) xs[tid]      = q[((size_t)b * S + i) * T + tid];
        else          xs[64 + (tid - 64)] = q[((size_t)b * S + i + 1) * T + (tid - 64)];
        __syncthreads();
        float s = 0.f;
        if (c < Dc) {
            const float* wr = W1 + (size_t)c * 256;   // W1[c][t][h]
            #pragma unroll 8
            for (int t = 0; t < 64; ++t) {
                s = fmaf(xs[t],      wr[2 * t],     s);
                s = fmaf(xs[64 + t], wr[2 * t + 1], s);
            }
            s += b1[c];
        }
        size_t row = ((size_t)b * SH + i) * CK + c;
        AqS[row] = s * s1 + u1;
        AqE[row] = s * s2 + u2;
    } else {                       // Ak row
        const int r = bid - NAQ;
        const int j = r % S, b = r / S;
        if (tid < 64) xs[tid] = kin[((size_t)b * S + j) * T + tid];
        __syncthreads();
        float s = 0.f;
        if (c < Dc) {
            const float* wr = W1 + (size_t)c * 256 + 128;
            #pragma unroll 8
            for (int t = 0; t < 64; ++t)
                s = fmaf(xs[t], wr[2 * t] + wr[2 * t + 1], s);
        }
        size_t row = ((size_t)b * S + j) * CK + c;
        AkS[row] = s * s1;
        AkE[row] = s * s2;
    }
}

// ---------------- k_main: merged-h K-loop. Ak frags loaded once per ks; both W2 halves in LDS ----------------
__global__ __launch_bounds__(256, 4) void k_main(const float* __restrict__ AqS, const float* __restrict__ AqE,
                                                 const float* __restrict__ AkS, const float* __restrict__ AkE,
                                                 const ush* __restrict__ W2p,
                                                 const float* __restrict__ U1, const float* __restrict__ S2,
                                                 const float* __restrict__ W30f, const float* __restrict__ W31f,
                                                 float* __restrict__ Z0, float* __restrict__ Z1) {
    __shared__ __align__(16) ush W2s[2 * CR * LSTR];   // both h halves (~61 KB)
    const int tid = threadIdx.x;
    const int wv = tid >> 6, lane = tid & 63, ln = lane & 15, quad = lane >> 4;
    const int jt = blockIdx.x, ip = blockIdx.y, b = blockIdx.z;
    const int j0 = jt << 7;
    const int jA = j0 + wv * 32 + ln;
    const int jB = jA + 16;

    floatx4 acc0[7], acc1[7];
    #pragma unroll
    for (int ct = 0; ct < 7; ++ct) {
        acc0[ct] = (floatx4){0.f, 0.f, 0.f, 0.f};
        acc1[ct] = (floatx4){0.f, 0.f, 0.f, 0.f};
    }

    // stage both W2 halves (rolled loop: keeps loads from being hoisted en masse)
    for (int idx = tid; idx < 2 * CR * 16; idx += 256) {
        int row = idx >> 4, ch = idx & 15;
        *reinterpret_cast<uint4*>(&W2s[row * LSTR + ch * 8]) =
            *reinterpret_cast<const uint4*>(&W2p[row * CK + ch * 8]);
    }
    __syncthreads();

    const float* aq0 = (ip == 0) ? U1 : (AqS + (size_t)(b * SH + ip - 1) * CK);  // h=0 row (pad -> relu(u1))
    const float* aq1 = AqS + (size_t)(b * SH + ip) * CK;                          // h=1 row
    const float* akrA = AkS + (size_t)(b * S + jA) * CK;
    const float* akrB = AkS + (size_t)(b * S + jB) * CK;

    #pragma unroll 1
    for (int ks = 0; ks < 4; ++ks) {
        const int k0 = ks * 32 + quad * 8;
        // Ak fragments: shared by both h phases
        const float4 ka = *reinterpret_cast<const float4*>(akrA + k0);
        const float4 kb = *reinterpret_cast<const float4*>(akrA + k0 + 4);
        const float4 kc = *reinterpret_cast<const float4*>(akrB + k0);
        const float4 kd = *reinterpret_cast<const float4*>(akrB + k0 + 4);
        // ---- h = 0 ----
        {
            const float4 qa = *reinterpret_cast<const float4*>(aq0 + k0);
            const float4 qb = *reinterpret_cast<const float4*>(aq0 + k0 + 4);
            uint4 p, rr;
            if (ip == 0) {
                p.x = pkbf(fmaxf(qa.x, 0.f), fmaxf(qa.y, 0.f));
                p.y = pkbf(fmaxf(qa.z, 0.f), fmaxf(qa.w, 0.f));
                p.z = pkbf(fmaxf(qb.x, 0.f), fmaxf(qb.y, 0.f));
                p.w = pkbf(fmaxf(qb.z, 0.f), fmaxf(qb.w, 0.f));
                rr = p;
            } else {
                p.x  = pkbf(fmaxf(qa.x + ka.x, 0.f), fmaxf(qa.y + ka.y, 0.f));
                p.y  = pkbf(fmaxf(qa.z + ka.z, 0.f), fmaxf(qa.w + ka.w, 0.f));
                p.z  = pkbf(fmaxf(qb.x + kb.x, 0.f), fmaxf(qb.y + kb.y, 0.f));
                p.w  = pkbf(fmaxf(qb.z + kb.z, 0.f), fmaxf(qb.w + kb.w, 0.f));
                rr.x = pkbf(fmaxf(qa.x + kc.x, 0.f), fmaxf(qa.y + kc.y, 0.f));
                rr.y = pkbf(fmaxf(qa.z + kc.z, 0.f), fmaxf(qa.w + kc.w, 0.f));
                rr.z = pkbf(fmaxf(qb.x + kd.x, 0.f), fmaxf(qb.y + kd.y, 0.f));
                rr.w = pkbf(fmaxf(qb.z + kd.z, 0.f), fmaxf(qb.w + kd.w, 0.f));
            }
            const bhalf8 bf0 = *reinterpret_cast<bhalf8*>(&p);
            const bhalf8 bf1 = *reinterpret_cast<bhalf8*>(&rr);
            #pragma unroll
            for (int ct = 0; ct < 7; ++ct) {
                const bhalf8 af = *reinterpret_cast<const bhalf8*>(&W2s[(ct * 16 + ln) * LSTR + k0]);
                acc0[ct] = __builtin_amdgcn_mfma_f32_16x16x32_bf16(af, bf0, acc0[ct], 0, 0, 0);
                acc1[ct] = __builtin_amdgcn_mfma_f32_16x16x32_bf16(af, bf1, acc1[ct], 0, 0, 0);
            }
        }
        // ---- h = 1 ----
        {
            const float4 qa = *reinterpret_cast<const float4*>(aq1 + k0);
            const float4 qb = *reinterpret_cast<const float4*>(aq1 + k0 + 4);
            uint4 p, rr;
            p.x  = pkbf(fmaxf(qa.x + ka.x, 0.f), fmaxf(qa.y + ka.y, 0.f));
            p.y  = pkbf(fmaxf(qa.z + ka.z, 0.f), fmaxf(qa.w + ka.w, 0.f));
            p.z  = pkbf(fmaxf(qb.x + kb.x, 0.f), fmaxf(qb.y + kb.y, 0.f));
            p.w  = pkbf(fmaxf(qb.z + kb.z, 0.f), fmaxf(qb.w + kb.w, 0.f));
            rr.x = pkbf(fmaxf(qa.x + kc.x, 0.f), fmaxf(qa.y + kc.y, 0.f));
            rr.y = pkbf(fmaxf(qa.z + kc.z, 0.f), fmaxf(qa.w + kc.w, 0.f));
            rr.z = pkbf(fmaxf(qb.x + kd.x, 0.f), fmaxf(qb.y + kd.y, 0.f));
            rr.w = pkbf(fmaxf(qb.z + kd.z, 0.f), fmaxf(qb.w + kd.w, 0.f));
            const bhalf8 bf0 = *reinterpret_cast<bhalf8*>(&p);
            const bhalf8 bf1 = *reinterpret_cast<bhalf8*>(&rr);
            #pragma unroll
            for (int ct = 0; ct < 7; ++ct) {
                const bhalf8 af = *reinterpret_cast<const bhalf8*>(&W2s[(CR + ct * 16 + ln) * LSTR + k0]);
                acc0[ct] = __builtin_amdgcn_mfma_f32_16x16x32_bf16(af, bf0, acc0[ct], 0, 0, 0);
                acc1[ct] = __builtin_amdgcn_mfma_f32_16x16x32_bf16(af, bf1, acc1[ct], 0, 0, 0);
            }
        }
    }

    // epilogue: ta = relu(acc*s2 + AqE[ip] + AkE[j]); conv3 taps z0/z1 reduced over c
    float z0a = 0.f, z1a = 0.f, z0b = 0.f, z1b = 0.f;
    const float* aqer = AqE + (size_t)(b * SH + ip) * CK;
    const float* akeA = AkE + (size_t)(b * S + jA) * CK;
    const float* akeB = AkE + (size_t)(b * S + jB) * CK;
    #pragma unroll
    for (int ct = 0; ct < 7; ++ct) {
        const int c = ct * 16 + (quad << 2);
        const float4 aq  = *reinterpret_cast<const float4*>(aqer + c);
        const float4 aka = *reinterpret_cast<const float4*>(akeA + c);
        const float4 akb = *reinterpret_cast<const float4*>(akeB + c);
        const float4 s2  = *reinterpret_cast<const float4*>(S2 + c);
        const float4 w0  = *reinterpret_cast<const float4*>(W30f + c);
        const float4 w1  = *reinterpret_cast<const float4*>(W31f + c);
        const float aqv[4] = {aq.x, aq.y, aq.z, aq.w};
        const float kav[4] = {aka.x, aka.y, aka.z, aka.w};
        const float kbv[4] = {akb.x, akb.y, akb.z, akb.w};
        const float s2v[4] = {s2.x, s2.y, s2.z, s2.w};
        const float w0v[4] = {w0.x, w0.y, w0.z, w0.w};
        const float w1v[4] = {w1.x, w1.y, w1.z, w1.w};
        #pragma unroll
        for (int r = 0; r < 4; ++r) {
            float ta = fmaxf(fmaf(acc0[ct][r], s2v[r], aqv[r] + kav[r]), 0.f);
            z0a = fmaf(ta, w0v[r], z0a);
            z1a = fmaf(ta, w1v[r], z1a);
            float tb = fmaxf(fmaf(acc1[ct][r], s2v[r], aqv[r] + kbv[r]), 0.f);
            z0b = fmaf(tb, w0v[r], z0b);
            z1b = fmaf(tb, w1v[r], z1b);
        }
    }
    z0a += __shfl_xor(z0a, 16, 64); z0a += __shfl_xor(z0a, 32, 64);
    z1a += __shfl_xor(z1a, 16, 64); z1a += __shfl_xor(z1a, 32, 64);
    z0b += __shfl_xor(z0b, 16, 64); z0b += __shfl_xor(z0b, 32, 64);
    z1b += __shfl_xor(z1b, 16, 64); z1b += __shfl_xor(z1b, 32, 64);
    if (lane < 16) {
        size_t zi = (size_t)(b * SH + ip) * S + j0 + wv * 32 + lane;
        Z0[zi] = z0a; Z1[zi] = z1a;
        Z0[zi + 16] = z0b; Z1[zi + 16] = z1b;
    }
}

// ---------------- softmax + attn@v: one wave per output row, no barriers ----------------
__global__ __launch_bounds__(256) void k_soft(const float* __restrict__ Z0, const float* __restrict__ Z1,
                                              const float* __restrict__ v,
                                              const float* __restrict__ b3,
                                              float* __restrict__ outp,
                                              float* __restrict__ attnp) {
    __shared__ float attn_s[4][256];
    const int wv = threadIdx.x >> 6, lane = threadIdx.x & 63;
    const int i = blockIdx.x * 4 + wv;
    const int b = blockIdx.y;
    if (i >= SO) return;
    const float b3f = b3[0];
    const size_t zr = (size_t)(b * SH + i) * S;
    const float4 z0 = *reinterpret_cast<const float4*>(Z0 + zr + lane * 4);
    const float4 z1 = *reinterpret_cast<const float4*>(Z1 + zr + S + lane * 4);
    float l0 = (z0.x + z1.x + b3f) * 0.1f;
    float l1 = (z0.y + z1.y + b3f) * 0.1f;
    float l2 = (z0.z + z1.z + b3f) * 0.1f;
    float l3 = (z0.w + z1.w + b3f) * 0.1f;

    float mx = fmaxf(fmaxf(l0, l1), fmaxf(l2, l3));
    #pragma unroll
    for (int o = 1; o < 64; o <<= 1) mx = fmaxf(mx, __shfl_xor(mx, o, 64));
    float e0 = __expf(l0 - mx), e1 = __expf(l1 - mx), e2 = __expf(l2 - mx), e3 = __expf(l3 - mx);
    float sm = e0 + e1 + e2 + e3;
    #pragma unroll
    for (int o = 1; o < 64; o <<= 1) sm += __shfl_xor(sm, o, 64);
    const float inv = 1.f / sm;
    const float a0 = e0 * inv, a1 = e1 * inv, a2 = e2 * inv, a3 = e3 * inv;
    *reinterpret_cast<float4*>(attnp + (size_t)(b * SO + i) * S + lane * 4) = make_float4(a0, a1, a2, a3);
    *reinterpret_cast<float4*>(&attn_s[wv][lane * 4]) = make_float4(a0, a1, a2, a3);
    // same-wave LDS RAW: no barrier needed

    const float* vb = v + (size_t)b * S * T + lane;
    float acc = 0.f;
    #pragma unroll 8
    for (int j = 0; j < 256; ++j)
        acc = fmaf(attn_s[wv][j], vb[(size_t)j * T], acc);
    outp[(size_t)(b * SO + i) * T + lane] = acc;
}

extern "C" void kernel_launch(void* const* d_in, const int* in_sizes, int n_in,
                              void* d_out, int out_size, void* d_ws, size_t ws_size,
                              hipStream_t stream) {
    const float* q    = (const float*)d_in[0];
    const float* kin  = (const float*)d_in[1];
    const float* vin  = (const float*)d_in[2];
    const float* W1   = (const float*)d_in[3];
    const float* b1   = (const float*)d_in[4];
    const float* g1   = (const float*)d_in[5];
    const float* be1  = (const float*)d_in[6];
    const float* m1   = (const float*)d_in[7];
    const float* var1 = (const float*)d_in[8];
    const float* W2   = (const float*)d_in[9];
    const float* b2   = (const float*)d_in[10];
    const float* g2   = (const float*)d_in[11];
    const float* be2  = (const float*)d_in[12];
    const float* m2   = (const float*)d_in[13];
    const float* var2 = (const float*)d_in[14];
    const float* W3   = (const float*)d_in[15];
    const float* b3   = (const float*)d_in[16];

    char* ws = (char*)d_ws;
    float* U1  = (float*)(ws + OFF_U1);
    float* S2p = (float*)(ws + OFF_S2);
    float* W30 = (float*)(ws + OFF_W30);
    float* W31 = (float*)(ws + OFF_W31);
    ush*   W2p = (ush*)(ws + OFF_W2P);
    float* AqS = (float*)(ws + OFF_AQS);
    float* AqE = (float*)(ws + OFF_AQE);
    float* AkS = (float*)(ws + OFF_AKS);
    float* AkE = (float*)(ws + OFF_AKE);
    float* Z0  = (float*)(ws + OFF_Z0);
    float* Z1  = (float*)(ws + OFF_Z1);

    float* outp  = (float*)d_out;
    float* attnp = outp + (size_t)Bb * SO * T;

    k_prep<<<NAQ + NAK + NW2 + 1, 128, 0, stream>>>(q, kin, W1, b1, g1, be1, m1, var1,
                                                    W2, b2, g2, be2, m2, var2, W3,
                                                    W2p, U1, S2p, W30, W31,
                                                    AqS, AqE, AkS, AkE);
    k_main<<<dim3(2, SH, Bb), 256, 0, stream>>>(AqS, AqE, AkS, AkE, W2p, U1, S2p, W30, W31, Z0, Z1);
    k_soft<<<dim3((SO + 3) / 4, Bb), 256, 0, stream>>>(Z0, Z1, vin, b3, outp, attnp);
}

// Round 7
// 202.563 us; speedup vs baseline: 1.4752x; 1.1503x over previous
//
#include <hip/hip_runtime.h>
#include <hip/hip_bf16.h>

typedef float floatx4 __attribute__((ext_vector_type(4)));
typedef short bhalf8  __attribute__((ext_vector_type(8)));
typedef unsigned short ush;
typedef unsigned int uint;

#define EPS 1e-5f

constexpr int Bb = 8, S = 256, T = 64, Dc = 100;
constexpr int SH = 255;   // conv2/y2 rows (S-H+1)
constexpr int SO = 254;   // final logit rows
constexpr int CK = 128;   // padded input-channel (K per h-tap)
constexpr int CR = 112;   // padded output-channel rows (7 x 16)

// workspace layout (bytes)
constexpr size_t OFF_U1   = 0;                            // f32[128]
constexpr size_t OFF_S2   = 512;                          // f32[128]
constexpr size_t OFF_W30  = 1024;                         // f32[128]
constexpr size_t OFF_W31  = 1536;                         // f32[128]
constexpr size_t OFF_W1T  = 2048;                         // f32 [128][128]
constexpr size_t OFF_W1KT = OFF_W1T + 65536;              // f32 [64][128]
constexpr size_t OFF_W2F  = OFF_W1KT + 32768;             // ush [2][4][7][64][8]  W2 in MFMA-A frag order
constexpr size_t OFF_AQS  = OFF_W2F + 57344;              // f32 [8][255][128]  Aq*s1+u1
constexpr size_t OFF_AQE  = OFF_AQS + (size_t)Bb*SH*CK*4; // f32 [8][255][128]  Aq*s2+u2
constexpr size_t OFF_AKF  = OFF_AQE + (size_t)Bb*SH*CK*4; // f32 [8][16][4][64][8]  Ak*s1, MFMA-B frag order
constexpr size_t OFF_AKEF = OFF_AKF + (size_t)Bb*16*4*64*8*4;  // f32 [8][16][7][64][4] Ak*s2, MFMA-C order
constexpr size_t OFF_Z0   = OFF_AKEF + (size_t)Bb*16*7*64*4*4; // f32 [8][255][256]
constexpr size_t OFF_Z1   = OFF_Z0 + (size_t)Bb*SH*S*4;   // f32 [8][255][256]

__device__ __forceinline__ uint pkbf(float lo, float hi) {
    // pack two f32 -> bf16x2 (+0x8000 round, high halves via one v_perm)
    uint a = __float_as_uint(lo) + 0x8000u;
    uint b = __float_as_uint(hi) + 0x8000u;
    return __builtin_amdgcn_perm(b, a, 0x07060302u);
}

// ---------------- prep0: W1 transposes + W2 fragment pack + per-channel params ----------------
__global__ __launch_bounds__(128) void k_prep0(const float* __restrict__ W1, const float* __restrict__ W2,
                                               const float* __restrict__ g1, const float* __restrict__ be1,
                                               const float* __restrict__ m1, const float* __restrict__ var1,
                                               const float* __restrict__ g2, const float* __restrict__ var2,
                                               const float* __restrict__ W3,
                                               float* __restrict__ W1T, float* __restrict__ W1kT,
                                               ush* __restrict__ W2F,
                                               float* __restrict__ U1, float* __restrict__ S2,
                                               float* __restrict__ W30, float* __restrict__ W31) {
    const int bid = blockIdx.x, tid = threadIdx.x;
    if (bid < 128) {                       // W1T[k][c] = W1[c][k]  (k = 2t+h, first 64 t-rows)
        int k = bid, c = tid;
        W1T[k * 128 + c] = (c < Dc) ? W1[(size_t)c * 256 + k] : 0.f;
    } else if (bid < 192) {                // W1kT[t][c] = W1[c][64+t][0] + W1[c][64+t][1]
        int t = bid - 128, c = tid;
        W1kT[t * 128 + c] = (c < Dc) ? (W1[(size_t)c * 256 + 128 + 2 * t] + W1[(size_t)c * 256 + 129 + 2 * t]) : 0.f;
    } else if (bid < 416) {                // W2 -> MFMA-A fragment order: [h][ks][ct][lane][e]
        int idx = (bid - 192) * 128 + tid;          // 0 .. 28671
        int h = idx / 14336;
        int r = idx % 14336;
        int ks = r / 3584;
        int r2 = r % 3584;
        int ct = r2 / 512;
        int r3 = r2 % 512;
        int lane = r3 >> 3, e = r3 & 7;
        int quad = lane >> 4, ln = lane & 15;
        int c = ct * 16 + ln;
        int cp = ks * 32 + quad * 8 + e;
        float v = (c < Dc && cp < Dc) ? W2[((size_t)c * Dc + cp) * 2 + h] : 0.f;
        __hip_bfloat16 bv = __float2bfloat16(v);
        W2F[idx] = *reinterpret_cast<ush*>(&bv);
    } else {                               // params
        int c = tid;
        float u1 = 0.f, s2 = 0.f, w0 = 0.f, w1 = 0.f;
        if (c < Dc) {
            float sg1 = g1[c] / sqrtf(var1[c] + EPS);
            u1 = be1[c] - m1[c] * sg1;
            s2 = g2[c] / sqrtf(var2[c] + EPS);
            w0 = W3[c * 2 + 0];
            w1 = W3[c * 2 + 1];
        }
        U1[c] = u1; S2[c] = s2; W30[c] = w0; W31[c] = w1;
    }
}

// ---------------- prep1: Aq rows (flat) / Ak rows (pre-swizzled MFMA lane order) ----------------
__global__ __launch_bounds__(128) void k_prep1(const float* __restrict__ q, const float* __restrict__ kin,
                                               const float* __restrict__ b1,
                                               const float* __restrict__ W1T, const float* __restrict__ W1kT,
                                               const float* __restrict__ g1, const float* __restrict__ be1,
                                               const float* __restrict__ m1, const float* __restrict__ var1,
                                               const float* __restrict__ g2, const float* __restrict__ be2,
                                               const float* __restrict__ m2, const float* __restrict__ var2,
                                               const float* __restrict__ b2,
                                               float* __restrict__ AqS, float* __restrict__ AqE,
                                               float* __restrict__ AkF, float* __restrict__ AkEF) {
    __shared__ float xs[128];
    const int bid = blockIdx.x, tid = threadIdx.x;
    const int c = tid;
    float s1 = 0.f, u1 = 0.f, s2 = 0.f, u2 = 0.f;
    if (c < Dc) {
        s1 = g1[c] / sqrtf(var1[c] + EPS);
        u1 = be1[c] - m1[c] * s1;
        s2 = g2[c] / sqrtf(var2[c] + EPS);
        u2 = (b2[c] - m2[c]) * s2 + be2[c];
    }
    if (bid < SH * Bb) {          // Aq row: i = bid % SH, b = bid / SH
        const int i = bid % SH, b = bid / SH;
        if (tid < 64) xs[2 * tid]            = q[((size_t)b * S + i) * T + tid];
        else          xs[2 * (tid - 64) + 1] = q[((size_t)b * S + i + 1) * T + (tid - 64)];
        __syncthreads();
        float s = 0.f;
        #pragma unroll 8
        for (int k = 0; k < 128; ++k) s = fmaf(xs[k], W1T[k * 128 + c], s);
        if (c < Dc) s += b1[c]; else s = 0.f;
        size_t row = ((size_t)b * SH + i) * CK + c;
        AqS[row] = s * s1 + u1;
        AqE[row] = s * s2 + u2;
    } else {                      // Ak row -> swizzled fragment buffers
        const int r = bid - SH * Bb;
        const int j = r % S, b = r / S;
        if (tid < 64) xs[tid] = kin[((size_t)b * S + j) * T + tid];
        __syncthreads();
        float s = 0.f;
        #pragma unroll 8
        for (int t = 0; t < 64; ++t) s = fmaf(xs[t], W1kT[t * 128 + c], s);
        const int j16 = j >> 4, ln = j & 15;
        // B-fragment layout: [b][j16][ks(4)][lane(64)=quad*16+ln][e(8)]
        {
            int ks = c >> 5, qq = (c >> 3) & 3, e = c & 7;
            AkF[((((size_t)b * 16 + j16) * 4 + ks) * 64 + qq * 16 + ln) * 8 + e] = s * s1;
        }
        // C-fragment layout: [b][j16][ct(7)][lane(64)=quad*16+ln][r(4)]
        if (c < 112) {
            int ct = c >> 4, q2 = (c >> 2) & 3, rr = c & 3;
            AkEF[((((size_t)b * 16 + j16) * 7 + ct) * 64 + q2 * 16 + ln) * 4 + rr] = s * s2;
        }
    }
}

// ---------------- k_main: NO LDS, no barriers. All operands in fragment order from global (L1/L2). ----------------
__global__ __launch_bounds__(256, 4) void k_main(const float* __restrict__ AqS, const float* __restrict__ AqE,
                                                 const float* __restrict__ AkF, const float* __restrict__ AkEF,
                                                 const ush* __restrict__ W2F,
                                                 const float* __restrict__ U1, const float* __restrict__ S2,
                                                 const float* __restrict__ W30f, const float* __restrict__ W31f,
                                                 float* __restrict__ Z0, float* __restrict__ Z1) {
    const int tid = threadIdx.x;
    const int wv = tid >> 6, lane = tid & 63, quad = lane >> 4;
    const int jt = blockIdx.x, ip = blockIdx.y, b = blockIdx.z;
    const int j0 = jt << 7;
    const int j16A = (jt << 3) + (wv << 1);

    floatx4 acc0[7], acc1[7];
    #pragma unroll
    for (int ct = 0; ct < 7; ++ct) {
        acc0[ct] = (floatx4){0.f, 0.f, 0.f, 0.f};
        acc1[ct] = (floatx4){0.f, 0.f, 0.f, 0.f};
    }

    const float* fA = AkF + ((size_t)(b * 16 + j16A) * 4 * 64 + lane) * 8;   // lane*32B coalesced
    const float* fB = fA + 4 * 64 * 8;
    const ush* wfl = W2F + lane * 8;                                          // lane*16B coalesced
    const float* aq0 = (ip == 0) ? U1 : (AqS + (size_t)(b * SH + ip - 1) * CK);
    const float* aq1 = AqS + (size_t)(b * SH + ip) * CK;
    const bool pad0 = (ip == 0);

    #pragma unroll 1
    for (int ks = 0; ks < 4; ++ks) {
        const int k0 = ks * 32 + quad * 8;
        // Ak fragments: shared by both h phases (loaded once)
        const float4 ka = *reinterpret_cast<const float4*>(fA + ks * 512);
        const float4 kb = *reinterpret_cast<const float4*>(fA + ks * 512 + 4);
        const float4 kc = *reinterpret_cast<const float4*>(fB + ks * 512);
        const float4 kd = *reinterpret_cast<const float4*>(fB + ks * 512 + 4);
        // ---- h = 0 ----
        {
            const float4 qa = *reinterpret_cast<const float4*>(aq0 + k0);
            const float4 qb = *reinterpret_cast<const float4*>(aq0 + k0 + 4);
            uint4 p, rr;
            if (pad0) {
                p.x = pkbf(fmaxf(qa.x, 0.f), fmaxf(qa.y, 0.f));
                p.y = pkbf(fmaxf(qa.z, 0.f), fmaxf(qa.w, 0.f));
                p.z = pkbf(fmaxf(qb.x, 0.f), fmaxf(qb.y, 0.f));
                p.w = pkbf(fmaxf(qb.z, 0.f), fmaxf(qb.w, 0.f));
                rr = p;
            } else {
                p.x  = pkbf(fmaxf(qa.x + ka.x, 0.f), fmaxf(qa.y + ka.y, 0.f));
                p.y  = pkbf(fmaxf(qa.z + ka.z, 0.f), fmaxf(qa.w + ka.w, 0.f));
                p.z  = pkbf(fmaxf(qb.x + kb.x, 0.f), fmaxf(qb.y + kb.y, 0.f));
                p.w  = pkbf(fmaxf(qb.z + kb.z, 0.f), fmaxf(qb.w + kb.w, 0.f));
                rr.x = pkbf(fmaxf(qa.x + kc.x, 0.f), fmaxf(qa.y + kc.y, 0.f));
                rr.y = pkbf(fmaxf(qa.z + kc.z, 0.f), fmaxf(qa.w + kc.w, 0.f));
                rr.z = pkbf(fmaxf(qb.x + kd.x, 0.f), fmaxf(qb.y + kd.y, 0.f));
                rr.w = pkbf(fmaxf(qb.z + kd.z, 0.f), fmaxf(qb.w + kd.w, 0.f));
            }
            const bhalf8 bf0 = *reinterpret_cast<bhalf8*>(&p);
            const bhalf8 bf1 = *reinterpret_cast<bhalf8*>(&rr);
            #pragma unroll
            for (int ct = 0; ct < 7; ++ct) {
                const bhalf8 af = *reinterpret_cast<const bhalf8*>(wfl + (size_t)(ks * 7 + ct) * 512);
                acc0[ct] = __builtin_amdgcn_mfma_f32_16x16x32_bf16(af, bf0, acc0[ct], 0, 0, 0);
                acc1[ct] = __builtin_amdgcn_mfma_f32_16x16x32_bf16(af, bf1, acc1[ct], 0, 0, 0);
            }
        }
        // ---- h = 1 ----
        {
            const float4 qa = *reinterpret_cast<const float4*>(aq1 + k0);
            const float4 qb = *reinterpret_cast<const float4*>(aq1 + k0 + 4);
            uint4 p, rr;
            p.x  = pkbf(fmaxf(qa.x + ka.x, 0.f), fmaxf(qa.y + ka.y, 0.f));
            p.y  = pkbf(fmaxf(qa.z + ka.z, 0.f), fmaxf(qa.w + ka.w, 0.f));
            p.z  = pkbf(fmaxf(qb.x + kb.x, 0.f), fmaxf(qb.y + kb.y, 0.f));
            p.w  = pkbf(fmaxf(qb.z + kb.z, 0.f), fmaxf(qb.w + kb.w, 0.f));
            rr.x = pkbf(fmaxf(qa.x + kc.x, 0.f), fmaxf(qa.y + kc.y, 0.f));
            rr.y = pkbf(fmaxf(qa.z + kc.z, 0.f), fmaxf(qa.w + kc.w, 0.f));
            rr.z = pkbf(fmaxf(qb.x + kd.x, 0.f), fmaxf(qb.y + kd.y, 0.f));
            rr.w = pkbf(fmaxf(qb.z + kd.z, 0.f), fmaxf(qb.w + kd.w, 0.f));
            const bhalf8 bf0 = *reinterpret_cast<bhalf8*>(&p);
            const bhalf8 bf1 = *reinterpret_cast<bhalf8*>(&rr);
            #pragma unroll
            for (int ct = 0; ct < 7; ++ct) {
                const bhalf8 af = *reinterpret_cast<const bhalf8*>(wfl + (size_t)((4 + ks) * 7 + ct) * 512);
                acc0[ct] = __builtin_amdgcn_mfma_f32_16x16x32_bf16(af, bf0, acc0[ct], 0, 0, 0);
                acc1[ct] = __builtin_amdgcn_mfma_f32_16x16x32_bf16(af, bf1, acc1[ct], 0, 0, 0);
            }
        }
    }

    // epilogue: ta = relu(acc*s2 + AqE[ip] + AkE[j]); conv3 taps z0/z1 reduced over c
    float z0a = 0.f, z1a = 0.f, z0b = 0.f, z1b = 0.f;
    const float* aqer = AqE + (size_t)(b * SH + ip) * CK;
    const float* eA = AkEF + ((size_t)(b * 16 + j16A) * 7 * 64 + lane) * 4;  // lane*16B coalesced
    const float* eB = eA + 7 * 64 * 4;
    #pragma unroll
    for (int ct = 0; ct < 7; ++ct) {
        const int c = ct * 16 + (quad << 2);
        const float4 aq  = *reinterpret_cast<const float4*>(aqer + c);
        const float4 aka = *reinterpret_cast<const float4*>(eA + ct * 256);
        const float4 akb = *reinterpret_cast<const float4*>(eB + ct * 256);
        const float4 s2  = *reinterpret_cast<const float4*>(S2 + c);
        const float4 w0  = *reinterpret_cast<const float4*>(W30f + c);
        const float4 w1  = *reinterpret_cast<const float4*>(W31f + c);
        const float aqv[4] = {aq.x, aq.y, aq.z, aq.w};
        const float kav[4] = {aka.x, aka.y, aka.z, aka.w};
        const float kbv[4] = {akb.x, akb.y, akb.z, akb.w};
        const float s2v[4] = {s2.x, s2.y, s2.z, s2.w};
        const float w0v[4] = {w0.x, w0.y, w0.z, w0.w};
        const float w1v[4] = {w1.x, w1.y, w1.z, w1.w};
        #pragma unroll
        for (int r = 0; r < 4; ++r) {
            float ta = fmaxf(fmaf(acc0[ct][r], s2v[r], aqv[r] + kav[r]), 0.f);
            z0a = fmaf(ta, w0v[r], z0a);
            z1a = fmaf(ta, w1v[r], z1a);
            float tb = fmaxf(fmaf(acc1[ct][r], s2v[r], aqv[r] + kbv[r]), 0.f);
            z0b = fmaf(tb, w0v[r], z0b);
            z1b = fmaf(tb, w1v[r], z1b);
        }
    }
    z0a += __shfl_xor(z0a, 16, 64); z0a += __shfl_xor(z0a, 32, 64);
    z1a += __shfl_xor(z1a, 16, 64); z1a += __shfl_xor(z1a, 32, 64);
    z0b += __shfl_xor(z0b, 16, 64); z0b += __shfl_xor(z0b, 32, 64);
    z1b += __shfl_xor(z1b, 16, 64); z1b += __shfl_xor(z1b, 32, 64);
    if (lane < 16) {
        size_t zi = (size_t)(b * SH + ip) * S + j0 + wv * 32 + lane;
        Z0[zi] = z0a; Z1[zi] = z1a;
        Z0[zi + 16] = z0b; Z1[zi + 16] = z1b;
    }
}

// ---------------- softmax + attn@v: one wave per output row, no barriers ----------------
__global__ __launch_bounds__(256) void k_soft(const float* __restrict__ Z0, const float* __restrict__ Z1,
                                              const float* __restrict__ v,
                                              const float* __restrict__ b3,
                                              float* __restrict__ outp,
                                              float* __restrict__ attnp) {
    __shared__ float attn_s[4][256];
    const int wv = threadIdx.x >> 6, lane = threadIdx.x & 63;
    const int i = blockIdx.x * 4 + wv;
    const int b = blockIdx.y;
    if (i >= SO) return;
    const float b3f = b3[0];
    const size_t zr = (size_t)(b * SH + i) * S;
    const float4 z0 = *reinterpret_cast<const float4*>(Z0 + zr + lane * 4);
    const float4 z1 = *reinterpret_cast<const float4*>(Z1 + zr + S + lane * 4);
    float l0 = (z0.x + z1.x + b3f) * 0.1f;
    float l1 = (z0.y + z1.y + b3f) * 0.1f;
    float l2 = (z0.z + z1.z + b3f) * 0.1f;
    float l3 = (z0.w + z1.w + b3f) * 0.1f;

    float mx = fmaxf(fmaxf(l0, l1), fmaxf(l2, l3));
    #pragma unroll
    for (int o = 1; o < 64; o <<= 1) mx = fmaxf(mx, __shfl_xor(mx, o, 64));
    float e0 = __expf(l0 - mx), e1 = __expf(l1 - mx), e2 = __expf(l2 - mx), e3 = __expf(l3 - mx);
    float sm = e0 + e1 + e2 + e3;
    #pragma unroll
    for (int o = 1; o < 64; o <<= 1) sm += __shfl_xor(sm, o, 64);
    const float inv = 1.f / sm;
    const float a0 = e0 * inv, a1 = e1 * inv, a2 = e2 * inv, a3 = e3 * inv;
    *reinterpret_cast<float4*>(attnp + (size_t)(b * SO + i) * S + lane * 4) = make_float4(a0, a1, a2, a3);
    *reinterpret_cast<float4*>(&attn_s[wv][lane * 4]) = make_float4(a0, a1, a2, a3);
    // same-wave LDS RAW: no barrier needed

    const float* vb = v + (size_t)b * S * T + lane;
    float acc = 0.f;
    #pragma unroll 8
    for (int j = 0; j < 256; ++j)
        acc = fmaf(attn_s[wv][j], vb[(size_t)j * T], acc);
    outp[(size_t)(b * SO + i) * T + lane] = acc;
}

extern "C" void kernel_launch(void* const* d_in, const int* in_sizes, int n_in,
                              void* d_out, int out_size, void* d_ws, size_t ws_size,
                              hipStream_t stream) {
    const float* q    = (const float*)d_in[0];
    const float* kin  = (const float*)d_in[1];
    const float* vin  = (const float*)d_in[2];
    const float* W1   = (const float*)d_in[3];
    const float* b1   = (const float*)d_in[4];
    const float* g1   = (const float*)d_in[5];
    const float* be1  = (const float*)d_in[6];
    const float* m1   = (const float*)d_in[7];
    const float* var1 = (const float*)d_in[8];
    const float* W2   = (const float*)d_in[9];
    const float* b2   = (const float*)d_in[10];
    const float* g2   = (const float*)d_in[11];
    const float* be2  = (const float*)d_in[12];
    const float* m2   = (const float*)d_in[13];
    const float* var2 = (const float*)d_in[14];
    const float* W3   = (const float*)d_in[15];
    const float* b3   = (const float*)d_in[16];

    char* ws = (char*)d_ws;
    float* U1   = (float*)(ws + OFF_U1);
    float* S2p  = (float*)(ws + OFF_S2);
    float* W30  = (float*)(ws + OFF_W30);
    float* W31  = (float*)(ws + OFF_W31);
    float* W1T  = (float*)(ws + OFF_W1T);
    float* W1kT = (float*)(ws + OFF_W1KT);
    ush*   W2F  = (ush*)(ws + OFF_W2F);
    float* AqS  = (float*)(ws + OFF_AQS);
    float* AqE  = (float*)(ws + OFF_AQE);
    float* AkF  = (float*)(ws + OFF_AKF);
    float* AkEF = (float*)(ws + OFF_AKEF);
    float* Z0   = (float*)(ws + OFF_Z0);
    float* Z1   = (float*)(ws + OFF_Z1);

    float* outp  = (float*)d_out;
    float* attnp = outp + (size_t)Bb * SO * T;

    k_prep0<<<417, 128, 0, stream>>>(W1, W2, g1, be1, m1, var1, g2, var2, W3,
                                     W1T, W1kT, W2F, U1, S2p, W30, W31);
    k_prep1<<<SH * Bb + S * Bb, 128, 0, stream>>>(q, kin, b1, W1T, W1kT,
                                                  g1, be1, m1, var1, g2, be2, m2, var2, b2,
                                                  AqS, AqE, AkF, AkEF);
    k_main<<<dim3(2, SH, Bb), 256, 0, stream>>>(AqS, AqE, AkF, AkEF, W2F, U1, S2p, W30, W31, Z0, Z1);
    k_soft<<<dim3((SO + 3) / 4, Bb), 256, 0, stream>>>(Z0, Z1, vin, b3, outp, attnp);
}

// Round 8
// 168.138 us; speedup vs baseline: 1.7773x; 1.2047x over previous
//
#include <hip/hip_runtime.h>
#include <hip/hip_bf16.h>

typedef float floatx4 __attribute__((ext_vector_type(4)));
typedef short bhalf8  __attribute__((ext_vector_type(8)));
typedef unsigned short ush;
typedef unsigned int uint;

#define EPS 1e-5f

constexpr int Bb = 8, S = 256, T = 64, Dc = 100;
constexpr int SH = 255;   // conv2/y2 rows (S-H+1)
constexpr int SO = 254;   // final logit rows
constexpr int CK = 128;   // padded input-channel (K per h-tap)
constexpr int CR = 112;   // padded output-channel rows (7 x 16)
constexpr int LSTR = 136; // LDS row stride in bf16 (272B)

// workspace layout (bytes)
constexpr size_t OFF_U1   = 0;                            // f32[128]
constexpr size_t OFF_S2   = 512;                          // f32[128]
constexpr size_t OFF_W30  = 1024;                         // f32[128]
constexpr size_t OFF_W31  = 1536;                         // f32[128]
constexpr size_t OFF_W1T  = 2048;                         // f32 [128][128]
constexpr size_t OFF_W1KT = OFF_W1T + 65536;              // f32 [64][128]
constexpr size_t OFF_W2P  = OFF_W1KT + 32768;             // ush [2][112][128] flat (for LDS staging)
constexpr size_t OFF_AQS  = OFF_W2P + 57344;              // f32 [8][255][128]  Aq*s1+u1
constexpr size_t OFF_AQE  = OFF_AQS + (size_t)Bb*SH*CK*4; // f32 [8][255][128]  Aq*s2+u2
constexpr size_t OFF_AKF  = OFF_AQE + (size_t)Bb*SH*CK*4; // f32 [8][16][4][64][8]  Ak*s1, MFMA-B frag order
constexpr size_t OFF_AKEF = OFF_AKF + (size_t)Bb*16*4*64*8*4;  // f32 [8][16][7][64][4] Ak*s2, MFMA-C order
constexpr size_t OFF_Z0   = OFF_AKEF + (size_t)Bb*16*7*64*4*4; // f32 [8][255][256]
constexpr size_t OFF_Z1   = OFF_Z0 + (size_t)Bb*SH*S*4;   // f32 [8][255][256]

__device__ __forceinline__ uint pkbf(float lo, float hi) {
    // pack two f32 -> bf16x2 (+0x8000 round, high halves via one v_perm)
    uint a = __float_as_uint(lo) + 0x8000u;
    uint b = __float_as_uint(hi) + 0x8000u;
    return __builtin_amdgcn_perm(b, a, 0x07060302u);
}

// ---------------- prep0: W1 transposes + W2 flat pack + per-channel params ----------------
__global__ __launch_bounds__(128) void k_prep0(const float* __restrict__ W1, const float* __restrict__ W2,
                                               const float* __restrict__ g1, const float* __restrict__ be1,
                                               const float* __restrict__ m1, const float* __restrict__ var1,
                                               const float* __restrict__ g2, const float* __restrict__ var2,
                                               const float* __restrict__ W3,
                                               float* __restrict__ W1T, float* __restrict__ W1kT,
                                               ush* __restrict__ W2p,
                                               float* __restrict__ U1, float* __restrict__ S2,
                                               float* __restrict__ W30, float* __restrict__ W31) {
    const int bid = blockIdx.x, tid = threadIdx.x;
    if (bid < 128) {                       // W1T[k][c] = W1[c][k]  (k = 2t+h, first 64 t-rows)
        int k = bid, c = tid;
        W1T[k * 128 + c] = (c < Dc) ? W1[(size_t)c * 256 + k] : 0.f;
    } else if (bid < 192) {                // W1kT[t][c] = W1[c][64+t][0] + W1[c][64+t][1]
        int t = bid - 128, c = tid;
        W1kT[t * 128 + c] = (c < Dc) ? (W1[(size_t)c * 256 + 128 + 2 * t] + W1[(size_t)c * 256 + 129 + 2 * t]) : 0.f;
    } else if (bid < 416) {                // W2 pack -> [h][c(112)][cp(128)] bf16, zero-padded
        int idx = (bid - 192) * 128 + tid;
        int h = idx / (CR * CK);
        int rem = idx % (CR * CK);
        int c = rem / CK, cp = rem % CK;
        float v = (c < Dc && cp < Dc) ? W2[((size_t)c * Dc + cp) * 2 + h] : 0.f;
        __hip_bfloat16 bv = __float2bfloat16(v);
        W2p[idx] = *reinterpret_cast<ush*>(&bv);
    } else {                               // params
        int c = tid;
        float u1 = 0.f, s2 = 0.f, w0 = 0.f, w1 = 0.f;
        if (c < Dc) {
            float sg1 = g1[c] / sqrtf(var1[c] + EPS);
            u1 = be1[c] - m1[c] * sg1;
            s2 = g2[c] / sqrtf(var2[c] + EPS);
            w0 = W3[c * 2 + 0];
            w1 = W3[c * 2 + 1];
        }
        U1[c] = u1; S2[c] = s2; W30[c] = w0; W31[c] = w1;
    }
}

// ---------------- prep1: Aq rows (flat) / Ak rows (pre-swizzled MFMA lane order) ----------------
__global__ __launch_bounds__(128) void k_prep1(const float* __restrict__ q, const float* __restrict__ kin,
                                               const float* __restrict__ b1,
                                               const float* __restrict__ W1T, const float* __restrict__ W1kT,
                                               const float* __restrict__ g1, const float* __restrict__ be1,
                                               const float* __restrict__ m1, const float* __restrict__ var1,
                                               const float* __restrict__ g2, const float* __restrict__ be2,
                                               const float* __restrict__ m2, const float* __restrict__ var2,
                                               const float* __restrict__ b2,
                                               float* __restrict__ AqS, float* __restrict__ AqE,
                                               float* __restrict__ AkF, float* __restrict__ AkEF) {
    __shared__ float xs[128];
    const int bid = blockIdx.x, tid = threadIdx.x;
    const int c = tid;
    float s1 = 0.f, u1 = 0.f, s2 = 0.f, u2 = 0.f;
    if (c < Dc) {
        s1 = g1[c] / sqrtf(var1[c] + EPS);
        u1 = be1[c] - m1[c] * s1;
        s2 = g2[c] / sqrtf(var2[c] + EPS);
        u2 = (b2[c] - m2[c]) * s2 + be2[c];
    }
    if (bid < SH * Bb) {          // Aq row: i = bid % SH, b = bid / SH
        const int i = bid % SH, b = bid / SH;
        if (tid < 64) xs[2 * tid]            = q[((size_t)b * S + i) * T + tid];
        else          xs[2 * (tid - 64) + 1] = q[((size_t)b * S + i + 1) * T + (tid - 64)];
        __syncthreads();
        float s = 0.f;
        #pragma unroll 8
        for (int k = 0; k < 128; ++k) s = fmaf(xs[k], W1T[k * 128 + c], s);
        if (c < Dc) s += b1[c]; else s = 0.f;
        size_t row = ((size_t)b * SH + i) * CK + c;
        AqS[row] = s * s1 + u1;
        AqE[row] = s * s2 + u2;
    } else {                      // Ak row -> swizzled fragment buffers
        const int r = bid - SH * Bb;
        const int j = r % S, b = r / S;
        if (tid < 64) xs[tid] = kin[((size_t)b * S + j) * T + tid];
        __syncthreads();
        float s = 0.f;
        #pragma unroll 8
        for (int t = 0; t < 64; ++t) s = fmaf(xs[t], W1kT[t * 128 + c], s);
        const int j16 = j >> 4, ln = j & 15;
        // B-fragment layout: [b][j16][ks(4)][lane(64)=quad*16+ln][e(8)]
        {
            int ks = c >> 5, qq = (c >> 3) & 3, e = c & 7;
            AkF[((((size_t)b * 16 + j16) * 4 + ks) * 64 + qq * 16 + ln) * 8 + e] = s * s1;
        }
        // C-fragment layout: [b][j16][ct(7)][lane(64)=quad*16+ln][r(4)]
        if (c < 112) {
            int ct = c >> 4, q2 = (c >> 2) & 3, rr = c & 3;
            AkEF[((((size_t)b * 16 + j16) * 7 + ct) * 64 + q2 * 16 + ln) * 4 + rr] = s * s2;
        }
    }
}

// ---------------- k_main: 512 threads = full (ip, j=0..255) row. LDS W2 shared by 8 waves;
// swizzled Ak frags (coalesced); merged-h rolled K-loop (r6 body = no spill). ----------------
__global__ __launch_bounds__(512, 4) void k_main(const float* __restrict__ AqS, const float* __restrict__ AqE,
                                                 const float* __restrict__ AkF, const float* __restrict__ AkEF,
                                                 const ush* __restrict__ W2p,
                                                 const float* __restrict__ U1, const float* __restrict__ S2,
                                                 const float* __restrict__ W30f, const float* __restrict__ W31f,
                                                 float* __restrict__ Z0, float* __restrict__ Z1) {
    __shared__ __align__(16) ush W2s[2 * CR * LSTR];   // both h halves (~61 KB)
    const int tid = threadIdx.x;
    const int wv = tid >> 6, lane = tid & 63, ln = lane & 15, quad = lane >> 4;
    const int ip = blockIdx.x, b = blockIdx.y;
    const int j16A = wv << 1;

    floatx4 acc0[7], acc1[7];
    #pragma unroll
    for (int ct = 0; ct < 7; ++ct) {
        acc0[ct] = (floatx4){0.f, 0.f, 0.f, 0.f};
        acc1[ct] = (floatx4){0.f, 0.f, 0.f, 0.f};
    }

    // stage both W2 halves (rolled: bounded live-set)
    for (int idx = tid; idx < 2 * CR * 16; idx += 512) {
        int row = idx >> 4, ch = idx & 15;
        *reinterpret_cast<uint4*>(&W2s[row * LSTR + ch * 8]) =
            *reinterpret_cast<const uint4*>(&W2p[row * CK + ch * 8]);
    }
    __syncthreads();

    const float* fA = AkF + ((size_t)(b * 16 + j16A) * 4 * 64 + lane) * 8;   // lane*32B coalesced
    const float* fB = fA + 4 * 64 * 8;
    const float* aq0 = (ip == 0) ? U1 : (AqS + (size_t)(b * SH + ip - 1) * CK);
    const float* aq1 = AqS + (size_t)(b * SH + ip) * CK;
    const bool pad0 = (ip == 0);

    #pragma unroll 1
    for (int ks = 0; ks < 4; ++ks) {
        const int k0 = ks * 32 + quad * 8;
        // Ak fragments: shared by both h phases (loaded once)
        const float4 ka = *reinterpret_cast<const float4*>(fA + ks * 512);
        const float4 kb = *reinterpret_cast<const float4*>(fA + ks * 512 + 4);
        const float4 kc = *reinterpret_cast<const float4*>(fB + ks * 512);
        const float4 kd = *reinterpret_cast<const float4*>(fB + ks * 512 + 4);
        // ---- h = 0 ----
        {
            const float4 qa = *reinterpret_cast<const float4*>(aq0 + k0);
            const float4 qb = *reinterpret_cast<const float4*>(aq0 + k0 + 4);
            uint4 p, rr;
            if (pad0) {
                p.x = pkbf(fmaxf(qa.x, 0.f), fmaxf(qa.y, 0.f));
                p.y = pkbf(fmaxf(qa.z, 0.f), fmaxf(qa.w, 0.f));
                p.z = pkbf(fmaxf(qb.x, 0.f), fmaxf(qb.y, 0.f));
                p.w = pkbf(fmaxf(qb.z, 0.f), fmaxf(qb.w, 0.f));
                rr = p;
            } else {
                p.x  = pkbf(fmaxf(qa.x + ka.x, 0.f), fmaxf(qa.y + ka.y, 0.f));
                p.y  = pkbf(fmaxf(qa.z + ka.z, 0.f), fmaxf(qa.w + ka.w, 0.f));
                p.z  = pkbf(fmaxf(qb.x + kb.x, 0.f), fmaxf(qb.y + kb.y, 0.f));
                p.w  = pkbf(fmaxf(qb.z + kb.z, 0.f), fmaxf(qb.w + kb.w, 0.f));
                rr.x = pkbf(fmaxf(qa.x + kc.x, 0.f), fmaxf(qa.y + kc.y, 0.f));
                rr.y = pkbf(fmaxf(qa.z + kc.z, 0.f), fmaxf(qa.w + kc.w, 0.f));
                rr.z = pkbf(fmaxf(qb.x + kd.x, 0.f), fmaxf(qb.y + kd.y, 0.f));
                rr.w = pkbf(fmaxf(qb.z + kd.z, 0.f), fmaxf(qb.w + kd.w, 0.f));
            }
            const bhalf8 bf0 = *reinterpret_cast<bhalf8*>(&p);
            const bhalf8 bf1 = *reinterpret_cast<bhalf8*>(&rr);
            #pragma unroll
            for (int ct = 0; ct < 7; ++ct) {
                const bhalf8 af = *reinterpret_cast<const bhalf8*>(&W2s[(ct * 16 + ln) * LSTR + k0]);
                acc0[ct] = __builtin_amdgcn_mfma_f32_16x16x32_bf16(af, bf0, acc0[ct], 0, 0, 0);
                acc1[ct] = __builtin_amdgcn_mfma_f32_16x16x32_bf16(af, bf1, acc1[ct], 0, 0, 0);
            }
        }
        // ---- h = 1 ----
        {
            const float4 qa = *reinterpret_cast<const float4*>(aq1 + k0);
            const float4 qb = *reinterpret_cast<const float4*>(aq1 + k0 + 4);
            uint4 p, rr;
            p.x  = pkbf(fmaxf(qa.x + ka.x, 0.f), fmaxf(qa.y + ka.y, 0.f));
            p.y  = pkbf(fmaxf(qa.z + ka.z, 0.f), fmaxf(qa.w + ka.w, 0.f));
            p.z  = pkbf(fmaxf(qb.x + kb.x, 0.f), fmaxf(qb.y + kb.y, 0.f));
            p.w  = pkbf(fmaxf(qb.z + kb.z, 0.f), fmaxf(qb.w + kb.w, 0.f));
            rr.x = pkbf(fmaxf(qa.x + kc.x, 0.f), fmaxf(qa.y + kc.y, 0.f));
            rr.y = pkbf(fmaxf(qa.z + kc.z, 0.f), fmaxf(qa.w + kc.w, 0.f));
            rr.z = pkbf(fmaxf(qb.x + kd.x, 0.f), fmaxf(qb.y + kd.y, 0.f));
            rr.w = pkbf(fmaxf(qb.z + kd.z, 0.f), fmaxf(qb.w + kd.w, 0.f));
            const bhalf8 bf0 = *reinterpret_cast<bhalf8*>(&p);
            const bhalf8 bf1 = *reinterpret_cast<bhalf8*>(&rr);
            #pragma unroll
            for (int ct = 0; ct < 7; ++ct) {
                const bhalf8 af = *reinterpret_cast<const bhalf8*>(&W2s[(CR + ct * 16 + ln) * LSTR + k0]);
                acc0[ct] = __builtin_amdgcn_mfma_f32_16x16x32_bf16(af, bf0, acc0[ct], 0, 0, 0);
                acc1[ct] = __builtin_amdgcn_mfma_f32_16x16x32_bf16(af, bf1, acc1[ct], 0, 0, 0);
            }
        }
    }

    // epilogue: ta = relu(acc*s2 + AqE[ip] + AkE[j]); conv3 taps z0/z1 reduced over c
    float z0a = 0.f, z1a = 0.f, z0b = 0.f, z1b = 0.f;
    const float* aqer = AqE + (size_t)(b * SH + ip) * CK;
    const float* eA = AkEF + ((size_t)(b * 16 + j16A) * 7 * 64 + lane) * 4;  // lane*16B coalesced
    const float* eB = eA + 7 * 64 * 4;
    #pragma unroll
    for (int ct = 0; ct < 7; ++ct) {
        const int c = ct * 16 + (quad << 2);
        const float4 aq  = *reinterpret_cast<const float4*>(aqer + c);
        const float4 aka = *reinterpret_cast<const float4*>(eA + ct * 256);
        const float4 akb = *reinterpret_cast<const float4*>(eB + ct * 256);
        const float4 s2  = *reinterpret_cast<const float4*>(S2 + c);
        const float4 w0  = *reinterpret_cast<const float4*>(W30f + c);
        const float4 w1  = *reinterpret_cast<const float4*>(W31f + c);
        const float aqv[4] = {aq.x, aq.y, aq.z, aq.w};
        const float kav[4] = {aka.x, aka.y, aka.z, aka.w};
        const float kbv[4] = {akb.x, akb.y, akb.z, akb.w};
        const float s2v[4] = {s2.x, s2.y, s2.z, s2.w};
        const float w0v[4] = {w0.x, w0.y, w0.z, w0.w};
        const float w1v[4] = {w1.x, w1.y, w1.z, w1.w};
        #pragma unroll
        for (int r = 0; r < 4; ++r) {
            float ta = fmaxf(fmaf(acc0[ct][r], s2v[r], aqv[r] + kav[r]), 0.f);
            z0a = fmaf(ta, w0v[r], z0a);
            z1a = fmaf(ta, w1v[r], z1a);
            float tb = fmaxf(fmaf(acc1[ct][r], s2v[r], aqv[r] + kbv[r]), 0.f);
            z0b = fmaf(tb, w0v[r], z0b);
            z1b = fmaf(tb, w1v[r], z1b);
        }
    }
    z0a += __shfl_xor(z0a, 16, 64); z0a += __shfl_xor(z0a, 32, 64);
    z1a += __shfl_xor(z1a, 16, 64); z1a += __shfl_xor(z1a, 32, 64);
    z0b += __shfl_xor(z0b, 16, 64); z0b += __shfl_xor(z0b, 32, 64);
    z1b += __shfl_xor(z1b, 16, 64); z1b += __shfl_xor(z1b, 32, 64);
    if (lane < 16) {
        size_t zi = (size_t)(b * SH + ip) * S + wv * 32 + lane;
        Z0[zi] = z0a; Z1[zi] = z1a;
        Z0[zi + 16] = z0b; Z1[zi + 16] = z1b;
    }
}

// ---------------- softmax + attn@v: one wave per output row, no barriers ----------------
__global__ __launch_bounds__(256) void k_soft(const float* __restrict__ Z0, const float* __restrict__ Z1,
                                              const float* __restrict__ v,
                                              const float* __restrict__ b3,
                                              float* __restrict__ outp,
                                              float* __restrict__ attnp) {
    __shared__ float attn_s[4][256];
    const int wv = threadIdx.x >> 6, lane = threadIdx.x & 63;
    const int i = blockIdx.x * 4 + wv;
    const int b = blockIdx.y;
    if (i >= SO) return;
    const float b3f = b3[0];
    const size_t zr = (size_t)(b * SH + i) * S;
    const float4 z0 = *reinterpret_cast<const float4*>(Z0 + zr + lane * 4);
    const float4 z1 = *reinterpret_cast<const float4*>(Z1 + zr + S + lane * 4);
    float l0 = (z0.x + z1.x + b3f) * 0.1f;
    float l1 = (z0.y + z1.y + b3f) * 0.1f;
    float l2 = (z0.z + z1.z + b3f) * 0.1f;
    float l3 = (z0.w + z1.w + b3f) * 0.1f;

    float mx = fmaxf(fmaxf(l0, l1), fmaxf(l2, l3));
    #pragma unroll
    for (int o = 1; o < 64; o <<= 1) mx = fmaxf(mx, __shfl_xor(mx, o, 64));
    float e0 = __expf(l0 - mx), e1 = __expf(l1 - mx), e2 = __expf(l2 - mx), e3 = __expf(l3 - mx);
    float sm = e0 + e1 + e2 + e3;
    #pragma unroll
    for (int o = 1; o < 64; o <<= 1) sm += __shfl_xor(sm, o, 64);
    const float inv = 1.f / sm;
    const float a0 = e0 * inv, a1 = e1 * inv, a2 = e2 * inv, a3 = e3 * inv;
    *reinterpret_cast<float4*>(attnp + (size_t)(b * SO + i) * S + lane * 4) = make_float4(a0, a1, a2, a3);
    *reinterpret_cast<float4*>(&attn_s[wv][lane * 4]) = make_float4(a0, a1, a2, a3);
    // same-wave LDS RAW: no barrier needed

    const float* vb = v + (size_t)b * S * T + lane;
    float acc = 0.f;
    #pragma unroll 8
    for (int j = 0; j < 256; ++j)
        acc = fmaf(attn_s[wv][j], vb[(size_t)j * T], acc);
    outp[(size_t)(b * SO + i) * T + lane] = acc;
}

extern "C" void kernel_launch(void* const* d_in, const int* in_sizes, int n_in,
                              void* d_out, int out_size, void* d_ws, size_t ws_size,
                              hipStream_t stream) {
    const float* q    = (const float*)d_in[0];
    const float* kin  = (const float*)d_in[1];
    const float* vin  = (const float*)d_in[2];
    const float* W1   = (const float*)d_in[3];
    const float* b1   = (const float*)d_in[4];
    const float* g1   = (const float*)d_in[5];
    const float* be1  = (const float*)d_in[6];
    const float* m1   = (const float*)d_in[7];
    const float* var1 = (const float*)d_in[8];
    const float* W2   = (const float*)d_in[9];
    const float* b2   = (const float*)d_in[10];
    const float* g2   = (const float*)d_in[11];
    const float* be2  = (const float*)d_in[12];
    const float* m2   = (const float*)d_in[13];
    const float* var2 = (const float*)d_in[14];
    const float* W3   = (const float*)d_in[15];
    const float* b3   = (const float*)d_in[16];

    char* ws = (char*)d_ws;
    float* U1   = (float*)(ws + OFF_U1);
    float* S2p  = (float*)(ws + OFF_S2);
    float* W30  = (float*)(ws + OFF_W30);
    float* W31  = (float*)(ws + OFF_W31);
    float* W1T  = (float*)(ws + OFF_W1T);
    float* W1kT = (float*)(ws + OFF_W1KT);
    ush*   W2p  = (ush*)(ws + OFF_W2P);
    float* AqS  = (float*)(ws + OFF_AQS);
    float* AqE  = (float*)(ws + OFF_AQE);
    float* AkF  = (float*)(ws + OFF_AKF);
    float* AkEF = (float*)(ws + OFF_AKEF);
    float* Z0   = (float*)(ws + OFF_Z0);
    float* Z1   = (float*)(ws + OFF_Z1);

    float* outp  = (float*)d_out;
    float* attnp = outp + (size_t)Bb * SO * T;

    k_prep0<<<417, 128, 0, stream>>>(W1, W2, g1, be1, m1, var1, g2, var2, W3,
                                     W1T, W1kT, W2p, U1, S2p, W30, W31);
    k_prep1<<<SH * Bb + S * Bb, 128, 0, stream>>>(q, kin, b1, W1T, W1kT,
                                                  g1, be1, m1, var1, g2, be2, m2, var2, b2,
                                                  AqS, AqE, AkF, AkEF);
    k_main<<<dim3(SH, Bb), 512, 0, stream>>>(AqS, AqE, AkF, AkEF, W2p, U1, S2p, W30, W31, Z0, Z1);
    k_soft<<<dim3((SO + 3) / 4, Bb), 256, 0, stream>>>(Z0, Z1, vin, b3, outp, attnp);
}